// Round 15
// baseline (116.334 us; speedup 1.0000x reference)
//
#include <hip/hip_runtime.h>

typedef unsigned short u16;
typedef u16 u16x4 __attribute__((ext_vector_type(4)));
typedef u16 u16x8 __attribute__((ext_vector_type(8)));
typedef __bf16 bf16x8 __attribute__((ext_vector_type(8)));
typedef float f32x4 __attribute__((ext_vector_type(4)));

#define DEVINL static __device__ __forceinline__

DEVINL u16 f2bf(float f) {
    unsigned u = __builtin_bit_cast(unsigned, f);
    u += 0x7fff + ((u >> 16) & 1);           // RNE
    return (u16)(u >> 16);
}

DEVINL u16 pbf(float f) {                    // round-half-up, for P in [0, 2^8]
    unsigned u = __builtin_bit_cast(unsigned, f);
    return (u16)((u + 0x8000) >> 16);
}

DEVINL f32x4 mfma_bf16(u16x8 a, u16x8 b, f32x4 c) {
    return __builtin_amdgcn_mfma_f32_16x16x32_bf16(
        __builtin_bit_cast(bf16x8, a), __builtin_bit_cast(bf16x8, b), c, 0, 0, 0);
}

DEVINL void gload16(const void* g, void* lds) {
    __builtin_amdgcn_global_load_lds(
        (const __attribute__((address_space(1))) void*)g,
        (__attribute__((address_space(3))) void*)lds, 16, 0, 0);
}

// ---------------- unified preprocessing kernel ----------------

DEVINL void twt_body(const float* __restrict__ src, u16* __restrict__ dst,
                     int N, int rowOff, int bx, int by, int tid, float (*t)[65]) {
    int k0 = bx * 64, n0 = by * 64;
#pragma unroll
    for (int j = 0; j < 16; j++) {
        int idx = j * 256 + tid; int r = idx >> 6, c = idx & 63;
        t[r][c] = src[(size_t)(k0 + r) * N + n0 + c];
    }
    __syncthreads();
#pragma unroll
    for (int j = 0; j < 16; j++) {
        int idx = j * 256 + tid; int r = idx >> 6, c = idx & 63;
        dst[(size_t)(rowOff + n0 + r) * 1024 + k0 + c] = f2bf(t[c][r]);
    }
}

__global__ void prep_kernel(const float* __restrict__ x,
                            const float* __restrict__ wq, const float* __restrict__ bq,
                            const float* __restrict__ wk, const float* __restrict__ bk,
                            const float* __restrict__ wv, const float* __restrict__ bv,
                            const float* __restrict__ wo,
                            u16* __restrict__ xb, u16* __restrict__ wqkvt,
                            u16* __restrict__ wot, float* __restrict__ bqkv) {
    __shared__ float t[64][65];
    int bid = blockIdx.x, tid = threadIdx.x;
    if (bid < 8192) {
        int idx = bid * 256 + tid;
        float4 a = ((const float4*)x)[idx];
        u16x4 o;
        o[0] = f2bf(a.x); o[1] = f2bf(a.y); o[2] = f2bf(a.z); o[3] = f2bf(a.w);
        ((u16x4*)xb)[idx] = o;
    } else if (bid < 8448) {
        int id = bid - 8192; twt_body(wq, wqkvt, 1024, 0, id & 15, id >> 4, tid, t);
    } else if (bid < 8512) {
        int id = bid - 8448; twt_body(wk, wqkvt, 256, 1024, id & 15, id >> 4, tid, t);
    } else if (bid < 8576) {
        int id = bid - 8512; twt_body(wv, wqkvt, 256, 1280, id & 15, id >> 4, tid, t);
    } else if (bid < 8832) {
        int id = bid - 8576; twt_body(wo, wot, 1024, 0, id & 15, id >> 4, tid, t);
    } else {
        int i = (bid - 8832) * 256 + tid;
        if (i < 1024) bqkv[i] = bq[i];
        else if (i < 1280) bqkv[i] = bk[i - 1024];
        else if (i < 1536) bqkv[i] = bv[i - 1280];
    }
}

// ---------------- MFMA GEMM (R10 structure + VSPLIT V-transpose epilogue) ----------------

template <bool F32OUT, bool VSPLIT>
__global__ __launch_bounds__(256, 2) void gemm_bt(
    const u16* __restrict__ A, const u16* __restrict__ Bt, void* __restrict__ Cp,
    const float* __restrict__ bias, u16* __restrict__ vt,
    int M, int N, int K, int qn, float qscale) {
    __shared__ __align__(16) u16 As[128 * 64];
    __shared__ __align__(16) u16 Bs[128 * 64];
    int tid = threadIdx.x; int l = tid & 63; int w = tid >> 6;

    int nwg = gridDim.x * gridDim.y;
    int lin = blockIdx.y * gridDim.x + blockIdx.x;
    int q_ = nwg >> 3, r_ = nwg & 7;
    int xcd = lin & 7, i_ = lin >> 3;
    int wgid = (xcd < r_ ? xcd * (q_ + 1) : r_ * (q_ + 1) + (xcd - r_) * q_) + i_;
    int m0 = (wgid / gridDim.x) * 128, n0 = (wgid % gridDim.x) * 128;

    int wm = (w >> 1) * 64, wn = (w & 1) * 64;
    f32x4 acc[4][4] = {};

    int srow[4], scol[4];
#pragma unroll
    for (int c = 0; c < 4; c++) {
        int b = (w * 4 + c) * 1024 + l * 16;
        int row = b >> 7, inner = b & 127;
        srow[c] = row;
        scol[c] = (inner ^ ((row & 7) << 4)) >> 1;
    }
    int nk = K >> 6;
    for (int kt = 0; kt < nk; ++kt) {
        int kb = kt << 6;
#pragma unroll
        for (int c = 0; c < 4; c++) {
            gload16(A + (size_t)(m0 + srow[c]) * K + kb + scol[c], (char*)As + (w * 4 + c) * 1024);
            gload16(Bt + (size_t)(n0 + srow[c]) * K + kb + scol[c], (char*)Bs + (w * 4 + c) * 1024);
        }
        __syncthreads();
#pragma unroll
        for (int kc = 0; kc < 2; ++kc) {
            int co = (kc * 32 + (l >> 4) * 8) * 2;
            u16x8 af[4], bf[4];
#pragma unroll
            for (int mf = 0; mf < 4; ++mf) {
                int row = wm + mf * 16 + (l & 15);
                af[mf] = *(const u16x8*)((const char*)As + row * 128 + (co ^ ((row & 7) << 4)));
            }
#pragma unroll
            for (int nf = 0; nf < 4; ++nf) {
                int row = wn + nf * 16 + (l & 15);
                bf[nf] = *(const u16x8*)((const char*)Bs + row * 128 + (co ^ ((row & 7) << 4)));
            }
#pragma unroll
            for (int mf = 0; mf < 4; ++mf)
#pragma unroll
                for (int nf = 0; nf < 4; ++nf)
                    acc[mf][nf] = mfma_bf16(af[mf], bf[nf], acc[mf][nf]);
        }
        __syncthreads();
    }
#pragma unroll
    for (int mf = 0; mf < 4; ++mf) {
#pragma unroll
        for (int nf = 0; nf < 4; ++nf) {
            int col = n0 + wn + nf * 16 + (l & 15);
            float bv = bias ? bias[col] : 0.0f;
            float scl = (col < qn) ? qscale : 1.0f;   // uniform per 16-lane group
            if (VSPLIT && col >= 1280) {
                int row0 = m0 + wm + mf * 16 + (l >> 4) * 4;
                int b_ = row0 >> 12, t_ = row0 & 4095;
                u16x4 pk;
#pragma unroll
                for (int r = 0; r < 4; r++) pk[r] = f2bf(acc[mf][nf][r] + bv);
                *(u16x4*)(vt + ((size_t)(b_ * 256 + (col - 1280)) << 12) + t_) = pk;
            } else {
#pragma unroll
                for (int r = 0; r < 4; r++) {
                    int row = m0 + wm + mf * 16 + (l >> 4) * 4 + r;
                    float v = (acc[mf][nf][r] + bv) * scl;
                    if (F32OUT) ((float*)Cp)[(size_t)row * N + col] = v;
                    else        ((u16*)Cp)[(size_t)row * N + col] = f2bf(v);
                }
            }
        }
    }
}

// ---------------- banded GQA flash attention: 128-row q-chunk, staged-once K/V ----------------
// block = (q-chunk of 128 rows, kv-head h, b); grid 32x4x2 = 256 = 1 block/CU.
// 8 waves = 4 q-heads x 2 row-halves; wave owns 4 fragments (rows sub*16 + j*32).
// ~10 K/V tiles staged ONCE per block (3.6x fewer stages/barriers than R8), each
// covering ~2-3 frag-tiles x 16 MFMA x 8 waves of compute (~1300-2300cy >> 500cy
// staging latency) -> single-sync prefetch (sync -> STAGE(t+1) -> compute(t)) hides.
// Per-(frag,tile) uniform relevance skip; interior frag-tiles skip elem masking.
// pmax floored at -60 (log2 domain) so all-masked lanes contribute exp2(-huge)=0.

__global__ __launch_bounds__(512) void attn_kernel(
    const u16* __restrict__ qkv, const u16* __restrict__ vt, u16* __restrict__ y) {
    __shared__ __align__(16) u16 Ks[2][64 * 64];
    __shared__ __align__(16) u16 Vs[2][64 * 64];
    __shared__ __align__(16) u16 Ps[8][16 * 64];
    int tid = threadIdx.x, l = tid & 63, w = tid >> 6;
    int chunk = blockIdx.x, h = blockIdx.y, b = blockIdx.z;
    int c0 = chunk * 128;
    size_t rowbase = (size_t)b * 4096;
    int head = w >> 1;                       // q-head within kv group
    int hq = h * 4 + head;
    int sub = w & 1;                         // 16-row offset within 32-row stripe

    // 4 q-fragments per wave: rows c0 + sub*16 + j*32 .. +15 (Q in log2 domain)
    u16x8 qf_[4][2];
#pragma unroll
    for (int j = 0; j < 4; ++j)
#pragma unroll
        for (int kc = 0; kc < 2; ++kc)
            qf_[j][kc] = *(const u16x8*)(qkv + (rowbase + c0 + sub * 16 + j * 32 + (l & 15)) * 1536
                                          + hq * 64 + kc * 32 + (l >> 4) * 8);

    f32x4 o[4][4] = {};
    float m_[4], s_[4];
#pragma unroll
    for (int j = 0; j < 4; ++j) { m_[j] = -__builtin_inff(); s_[j] = 0.f; }

    const u16* kbase_ptr = qkv + 1024 + h * 64;
    const u16* vbase_ptr = vt + (size_t)((b * 4 + h) * 64) * 4096;

    // per-wave staging chunk (1 KiB each of K and V), pre-swizzled source
    int sb_ = w * 1024 + l * 16;
    int g_row = sb_ >> 7, g_inner = sb_ & 127;
    int g_col = (g_inner ^ ((g_row & 7) << 4)) >> 1;

    int klo = c0 - 256; if (klo < 0) klo = 0;
    int khi = c0 + 127 + 256; if (khi > 4095) khi = 4095;
    khi &= ~63;                              // last tile start
    int nt = ((khi - klo) >> 6) + 1;

#define STAGE(bufi, ks_)                                                                  \
    do {                                                                                  \
        gload16(kbase_ptr + (rowbase + (ks_) + g_row) * 1536 + g_col,                     \
                (char*)Ks[bufi] + w * 1024);                                              \
        gload16(vbase_ptr + (size_t)g_row * 4096 + (ks_) + g_col,                         \
                (char*)Vs[bufi] + w * 1024);                                              \
    } while (0)

    STAGE(0, klo);
    for (int t = 0; t < nt; ++t) {
        int kstart = klo + (t << 6);
        int par = t & 1;
        __syncthreads();                     // prefetch from last iter has landed
        if (t + 1 < nt) STAGE(par ^ 1, kstart + 64);
        const char* Kb = (const char*)Ks[par];
        const char* Vb = (const char*)Vs[par];

#pragma unroll
        for (int j = 0; j < 4; ++j) {
            int qlo = c0 + sub * 16 + j * 32;
            int qhi = qlo + 15;
            if (kstart + 63 < qlo - 256 || kstart > qhi + 256) continue;   // uniform skip

            // S^T[key][q] = K * Q^T (log2 domain)
            f32x4 st[4] = {};
#pragma unroll
            for (int kc = 0; kc < 2; ++kc) {
                int co = (kc * 32 + (l >> 4) * 8) * 2;
#pragma unroll
                for (int kf = 0; kf < 4; ++kf) {
                    int row = kf * 16 + (l & 15);
                    u16x8 kfr = *(const u16x8*)(Kb + row * 128 + (co ^ ((row & 7) << 4)));
                    st[kf] = mfma_bf16(kfr, qf_[j][kc], st[kf]);
                }
            }

            bool interior = (kstart >= qhi - 256) && (kstart + 63 <= qlo + 256);
            float pmax = -1e30f;
            float sv[4][4];
            if (interior) {
#pragma unroll
                for (int kf = 0; kf < 4; ++kf)
#pragma unroll
                    for (int r = 0; r < 4; r++) {
                        sv[kf][r] = st[kf][r];
                        pmax = fmaxf(pmax, sv[kf][r]);
                    }
            } else {
                int qp = qlo + (l & 15);
#pragma unroll
                for (int kf = 0; kf < 4; ++kf)
#pragma unroll
                    for (int r = 0; r < 4; r++) {
                        int koff = kstart + kf * 16 + (l >> 4) * 4 + r;
                        float v = st[kf][r];
                        if (koff < qp - 256 || koff > qp + 256) v = -1e30f;
                        sv[kf][r] = v;
                        pmax = fmaxf(pmax, v);
                    }
            }
            pmax = fmaxf(pmax, __shfl_xor(pmax, 16));
            pmax = fmaxf(pmax, __shfl_xor(pmax, 32));
            pmax = fmaxf(pmax, -60.0f);      // all-masked-lane safety floor

            bool resc = !__all(pmax - m_[j] <= 8.0f);
            float newm = resc ? fmaxf(m_[j], pmax) : m_[j];
            float psum = 0.f;
#pragma unroll
            for (int kf = 0; kf < 4; ++kf) {
                u16x4 pk;
#pragma unroll
                for (int r = 0; r < 4; r++) {
                    float e = __builtin_amdgcn_exp2f(sv[kf][r] - newm);
                    psum += e;
                    pk[r] = pbf(e);
                }
                int row = l & 15;
                int keyc = kf * 16 + (l >> 4) * 4;
                *(u16x4*)((char*)Ps[w] + ((row * 128 + keyc * 2) ^ ((row & 7) << 4))) = pk;
            }
            psum += __shfl_xor(psum, 16);
            psum += __shfl_xor(psum, 32);
            if (resc) {
                float fs = __builtin_amdgcn_exp2f(m_[j] - newm);
                s_[j] = s_[j] * fs + psum;
                m_[j] = newm;
#pragma unroll
                for (int r = 0; r < 4; r++) {
                    float fb = __shfl(fs, (l >> 4) * 4 + r);
#pragma unroll
                    for (int nf = 0; nf < 4; ++nf) o[j][nf][r] *= fb;
                }
            } else {
                s_[j] += psum;
            }

            // O += P * V
#pragma unroll
            for (int kc = 0; kc < 2; ++kc) {
                int co = (kc * 32 + (l >> 4) * 8) * 2;
                int prow = l & 15;
                u16x8 pa = *(const u16x8*)((const char*)Ps[w] + ((prow * 128 + co) ^ ((prow & 7) << 4)));
#pragma unroll
                for (int nf = 0; nf < 4; ++nf) {
                    int row = nf * 16 + (l & 15);
                    u16x8 vb = *(const u16x8*)(Vb + row * 128 + (co ^ ((row & 7) << 4)));
                    o[j][nf] = mfma_bf16(pa, vb, o[j][nf]);
                }
            }
        }
    }
#undef STAGE

    // normalize + store y bf16 [8192][1024]
#pragma unroll
    for (int j = 0; j < 4; ++j) {
        float inv = 1.0f / s_[j];
#pragma unroll
        for (int r = 0; r < 4; r++) {
            float sb = __shfl(inv, (l >> 4) * 4 + r);
            int row = c0 + sub * 16 + j * 32 + (l >> 4) * 4 + r;
#pragma unroll
            for (int nf = 0; nf < 4; ++nf) {
                int col = hq * 64 + nf * 16 + (l & 15);
                y[(rowbase + row) * 1024 + col] = f2bf(o[j][nf][r] * sb);
            }
        }
    }
}

// ---------------- host launch ----------------

extern "C" void kernel_launch(void* const* d_in, const int* in_sizes, int n_in,
                              void* d_out, int out_size, void* d_ws, size_t ws_size,
                              hipStream_t stream) {
    const float* x  = (const float*)d_in[0];
    const float* wq = (const float*)d_in[1];
    const float* bq = (const float*)d_in[2];
    const float* wk = (const float*)d_in[3];
    const float* bk = (const float*)d_in[4];
    const float* wv = (const float*)d_in[5];
    const float* bv = (const float*)d_in[6];
    const float* wo = (const float*)d_in[7];
    const float* bo = (const float*)d_in[8];
    float* out = (float*)d_out;

    char* p = (char*)d_ws;
    u16* xb     = (u16*)p;   p += (size_t)8192 * 1024 * 2;   // x bf16
    u16* wqkvt  = (u16*)p;   p += (size_t)1536 * 1024 * 2;   // [n][k] bf16 (q,k,v concat)
    u16* wot    = (u16*)p;   p += (size_t)1024 * 1024 * 2;   // wo^T bf16
    float* bqkv = (float*)p; p += 8192;                      // 1536 fp32 (padded)
    u16* qkvb   = (u16*)p;   p += (size_t)8192 * 1536 * 2;   // QKV bf16 (V-section unused)
    u16* vtb    = (u16*)p;   p += (size_t)512 * 4096 * 2;    // V^T bf16
    u16* yb     = (u16*)p;                                   // attn out bf16

    prep_kernel<<<8838, 256, 0, stream>>>(x, wq, bq, wk, bk, wv, bv, wo,
                                          xb, wqkvt, wot, bqkv);

    // Q columns pre-scaled by 0.125*log2(e); V n-tiles written transposed to vtb
    gemm_bt<false, true><<<dim3(12, 64), 256, 0, stream>>>(xb, wqkvt, qkvb, bqkv, vtb,
                                                           8192, 1536, 1024, 1024, 0.18033688f);
    attn_kernel<<<dim3(32, 4, 2), 512, 0, stream>>>(qkvb, vtb, yb);
    gemm_bt<true, false><<<dim3(8, 64), 256, 0, stream>>>(yb, wot, out, bo, nullptr,
                                                          8192, 1024, 1024, 0, 1.0f);
}

// Round 16
// 107.982 us; speedup vs baseline: 1.0773x; 1.0773x over previous
//
#include <hip/hip_runtime.h>

typedef unsigned short u16;
typedef u16 u16x4 __attribute__((ext_vector_type(4)));
typedef u16 u16x8 __attribute__((ext_vector_type(8)));
typedef __bf16 bf16x8 __attribute__((ext_vector_type(8)));
typedef float f32x4 __attribute__((ext_vector_type(4)));

#define DEVINL static __device__ __forceinline__

DEVINL u16 f2bf(float f) {
    unsigned u = __builtin_bit_cast(unsigned, f);
    u += 0x7fff + ((u >> 16) & 1);           // RNE
    return (u16)(u >> 16);
}

DEVINL u16 pbf(float f) {                    // round-half-up, for P in [0, 2^8]
    unsigned u = __builtin_bit_cast(unsigned, f);
    return (u16)((u + 0x8000) >> 16);
}

DEVINL f32x4 mfma_bf16(u16x8 a, u16x8 b, f32x4 c) {
    return __builtin_amdgcn_mfma_f32_16x16x32_bf16(
        __builtin_bit_cast(bf16x8, a), __builtin_bit_cast(bf16x8, b), c, 0, 0, 0);
}

DEVINL void gload16(const void* g, void* lds) {
    __builtin_amdgcn_global_load_lds(
        (const __attribute__((address_space(1))) void*)g,
        (__attribute__((address_space(3))) void*)lds, 16, 0, 0);
}

// ---------------- unified preprocessing kernel (R13: fused, -9.6us) ----------------

DEVINL void twt_body(const float* __restrict__ src, u16* __restrict__ dst,
                     int N, int rowOff, int bx, int by, int tid, float (*t)[65]) {
    int k0 = bx * 64, n0 = by * 64;
#pragma unroll
    for (int j = 0; j < 16; j++) {
        int idx = j * 256 + tid; int r = idx >> 6, c = idx & 63;
        t[r][c] = src[(size_t)(k0 + r) * N + n0 + c];
    }
    __syncthreads();
#pragma unroll
    for (int j = 0; j < 16; j++) {
        int idx = j * 256 + tid; int r = idx >> 6, c = idx & 63;
        dst[(size_t)(rowOff + n0 + r) * 1024 + k0 + c] = f2bf(t[c][r]);
    }
}

__global__ void prep_kernel(const float* __restrict__ x,
                            const float* __restrict__ wq, const float* __restrict__ bq,
                            const float* __restrict__ wk, const float* __restrict__ bk,
                            const float* __restrict__ wv, const float* __restrict__ bv,
                            const float* __restrict__ wo,
                            u16* __restrict__ xb, u16* __restrict__ wqkvt,
                            u16* __restrict__ wot, float* __restrict__ bqkv) {
    __shared__ float t[64][65];
    int bid = blockIdx.x, tid = threadIdx.x;
    if (bid < 8192) {
        int idx = bid * 256 + tid;
        float4 a = ((const float4*)x)[idx];
        u16x4 o;
        o[0] = f2bf(a.x); o[1] = f2bf(a.y); o[2] = f2bf(a.z); o[3] = f2bf(a.w);
        ((u16x4*)xb)[idx] = o;
    } else if (bid < 8448) {
        int id = bid - 8192; twt_body(wq, wqkvt, 1024, 0, id & 15, id >> 4, tid, t);
    } else if (bid < 8512) {
        int id = bid - 8448; twt_body(wk, wqkvt, 256, 1024, id & 15, id >> 4, tid, t);
    } else if (bid < 8576) {
        int id = bid - 8512; twt_body(wv, wqkvt, 256, 1280, id & 15, id >> 4, tid, t);
    } else if (bid < 8832) {
        int id = bid - 8576; twt_body(wo, wot, 1024, 0, id & 15, id >> 4, tid, t);
    } else {
        int i = (bid - 8832) * 256 + tid;
        if (i < 1024) bqkv[i] = bq[i];
        else if (i < 1280) bqkv[i] = bk[i - 1024];
        else if (i < 1536) bqkv[i] = bv[i - 1280];
    }
}

// ---------------- MFMA GEMM (R10 structure + R14 VSPLIT V-transpose epilogue) ----------------
// Bijective chunked XCD swizzle (m204): ~10us win measured R5->R6.
// VSPLIT: cols >= 1280 (whole n-tiles) written directly transposed into vt,
// replacing the separate tv_kernel pass (R14: -2us); qkvb V-section never read.

template <bool F32OUT, bool VSPLIT>
__global__ __launch_bounds__(256, 2) void gemm_bt(
    const u16* __restrict__ A, const u16* __restrict__ Bt, void* __restrict__ Cp,
    const float* __restrict__ bias, u16* __restrict__ vt,
    int M, int N, int K, int qn, float qscale) {
    __shared__ __align__(16) u16 As[128 * 64];
    __shared__ __align__(16) u16 Bs[128 * 64];
    int tid = threadIdx.x; int l = tid & 63; int w = tid >> 6;

    int nwg = gridDim.x * gridDim.y;
    int lin = blockIdx.y * gridDim.x + blockIdx.x;
    int q_ = nwg >> 3, r_ = nwg & 7;
    int xcd = lin & 7, i_ = lin >> 3;
    int wgid = (xcd < r_ ? xcd * (q_ + 1) : r_ * (q_ + 1) + (xcd - r_) * q_) + i_;
    int m0 = (wgid / gridDim.x) * 128, n0 = (wgid % gridDim.x) * 128;

    int wm = (w >> 1) * 64, wn = (w & 1) * 64;
    f32x4 acc[4][4] = {};

    int srow[4], scol[4];
#pragma unroll
    for (int c = 0; c < 4; c++) {
        int b = (w * 4 + c) * 1024 + l * 16;
        int row = b >> 7, inner = b & 127;
        srow[c] = row;
        scol[c] = (inner ^ ((row & 7) << 4)) >> 1;
    }
    int nk = K >> 6;
    for (int kt = 0; kt < nk; ++kt) {
        int kb = kt << 6;
#pragma unroll
        for (int c = 0; c < 4; c++) {
            gload16(A + (size_t)(m0 + srow[c]) * K + kb + scol[c], (char*)As + (w * 4 + c) * 1024);
            gload16(Bt + (size_t)(n0 + srow[c]) * K + kb + scol[c], (char*)Bs + (w * 4 + c) * 1024);
        }
        __syncthreads();
#pragma unroll
        for (int kc = 0; kc < 2; ++kc) {
            int co = (kc * 32 + (l >> 4) * 8) * 2;
            u16x8 af[4], bf[4];
#pragma unroll
            for (int mf = 0; mf < 4; ++mf) {
                int row = wm + mf * 16 + (l & 15);
                af[mf] = *(const u16x8*)((const char*)As + row * 128 + (co ^ ((row & 7) << 4)));
            }
#pragma unroll
            for (int nf = 0; nf < 4; ++nf) {
                int row = wn + nf * 16 + (l & 15);
                bf[nf] = *(const u16x8*)((const char*)Bs + row * 128 + (co ^ ((row & 7) << 4)));
            }
#pragma unroll
            for (int mf = 0; mf < 4; ++mf)
#pragma unroll
                for (int nf = 0; nf < 4; ++nf)
                    acc[mf][nf] = mfma_bf16(af[mf], bf[nf], acc[mf][nf]);
        }
        __syncthreads();
    }
#pragma unroll
    for (int mf = 0; mf < 4; ++mf) {
#pragma unroll
        for (int nf = 0; nf < 4; ++nf) {
            int col = n0 + wn + nf * 16 + (l & 15);
            float bv = bias ? bias[col] : 0.0f;
            float scl = (col < qn) ? qscale : 1.0f;   // uniform per 16-lane group
            if (VSPLIT && col >= 1280) {
                int row0 = m0 + wm + mf * 16 + (l >> 4) * 4;
                int b_ = row0 >> 12, t_ = row0 & 4095;
                u16x4 pk;
#pragma unroll
                for (int r = 0; r < 4; r++) pk[r] = f2bf(acc[mf][nf][r] + bv);
                *(u16x4*)(vt + ((size_t)(b_ * 256 + (col - 1280)) << 12) + t_) = pk;
            } else {
#pragma unroll
                for (int r = 0; r < 4; r++) {
                    int row = m0 + wm + mf * 16 + (l >> 4) * 4 + r;
                    float v = (acc[mf][nf][r] + bv) * scl;
                    if (F32OUT) ((float*)Cp)[(size_t)row * N + col] = v;
                    else        ((u16*)Cp)[(size_t)row * N + col] = f2bf(v);
                }
            }
        }
    }
}

// ---------------- banded GQA flash attention (R8 structure, measured 41.7us) ----------------
// block = (qblock 64, head-pair, b); grid 64x8x2 = 1024 blocks = 4/CU.
// 8 waves = 2 q-heads x 4 q-fragments (16 rows each). LDS 32KB, VGPR 48.
// FROZEN: 7 structural perturbations (R4 counted-vmcnt, R6 dbuf-prefetch, R7
// forced-occupancy, R9 barrier-free, R11 small-blocks, R15 big-chunks) all
// regressed. 4 co-resident 8-wave blocks/CU + single-buffer 2-barrier loop is
// the empirical optimum for this latency-bound regime.

__global__ __launch_bounds__(512, 4) void attn_kernel(
    const u16* __restrict__ qkv, const u16* __restrict__ vt, u16* __restrict__ y) {
    __shared__ __align__(16) u16 Ks[64 * 64];
    __shared__ __align__(16) u16 Vs[64 * 64];
    __shared__ __align__(16) u16 Ps[8][16 * 64];
    int tid = threadIdx.x, l = tid & 63, w = tid >> 6;
    int qb = ((blockIdx.x & 7) << 3) | (blockIdx.x >> 3);
    int h = blockIdx.y >> 1, hp = blockIdx.y & 1, b = blockIdx.z;
    int qstart = qb * 64;
    size_t rowbase = (size_t)b * 4096;
    int hq = h * 4 + hp * 2 + (w >> 2);
    int qrow0 = (w & 3) * 16;

    u16x8 qf_[2];
#pragma unroll
    for (int kc = 0; kc < 2; ++kc)
        qf_[kc] = *(const u16x8*)(qkv + (rowbase + qstart + qrow0 + (l & 15)) * 1536
                                  + hq * 64 + kc * 32 + (l >> 4) * 8);

    f32x4 o[4] = {};
    float mrow = -__builtin_inff(), srow_ = 0.f;

    const u16* kbase_ptr = qkv + 1024 + h * 64;
    const u16* vbase_ptr = vt + (size_t)((b * 4 + h) * 64) * 4096;

    int sb_ = w * 1024 + l * 16;
    int g_row = sb_ >> 7, g_inner = sb_ & 127;
    int g_col = (g_inner ^ ((g_row & 7) << 4)) >> 1;

#pragma unroll
    for (int kstart = qstart - 256; kstart <= qstart + 256; kstart += 64) {
        if (kstart < 0 || kstart >= 4096) continue;
        gload16(kbase_ptr + (rowbase + kstart + g_row) * 1536 + g_col, (char*)Ks + w * 1024);
        gload16(vbase_ptr + (size_t)g_row * 4096 + kstart + g_col, (char*)Vs + w * 1024);
        __syncthreads();

        f32x4 st[4] = {};
#pragma unroll
        for (int kc = 0; kc < 2; ++kc) {
            int co = (kc * 32 + (l >> 4) * 8) * 2;
#pragma unroll
            for (int kf = 0; kf < 4; ++kf) {
                int row = kf * 16 + (l & 15);
                u16x8 kfr = *(const u16x8*)((const char*)Ks + row * 128 + (co ^ ((row & 7) << 4)));
                st[kf] = mfma_bf16(kfr, qf_[kc], st[kf]);
            }
        }

        bool mlo = (kstart == qstart - 256);
        bool mhi = (kstart == qstart + 256);

        int qoff = qrow0 + (l & 15);
        float pmax = -1e30f;
        float sv[4][4];
#pragma unroll
        for (int kf = 0; kf < 4; ++kf)
#pragma unroll
            for (int r = 0; r < 4; r++) {
                int koff = kf * 16 + (l >> 4) * 4 + r;
                float v = st[kf][r];
                if (mlo && koff < qoff) v = -1e30f;
                if (mhi && koff > qoff) v = -1e30f;
                sv[kf][r] = v;
                pmax = fmaxf(pmax, v);
            }
        pmax = fmaxf(pmax, __shfl_xor(pmax, 16));
        pmax = fmaxf(pmax, __shfl_xor(pmax, 32));

        bool resc = !__all(pmax - mrow <= 8.0f);
        float newm = resc ? fmaxf(mrow, pmax) : mrow;
        float psum = 0.f;
#pragma unroll
        for (int kf = 0; kf < 4; ++kf) {
            u16x4 pk;
#pragma unroll
            for (int r = 0; r < 4; r++) {
                float e = __builtin_amdgcn_exp2f(sv[kf][r] - newm);
                psum += e;
                pk[r] = pbf(e);
            }
            int row = l & 15;
            int keyc = kf * 16 + (l >> 4) * 4;
            *(u16x4*)((char*)Ps[w] + ((row * 128 + keyc * 2) ^ ((row & 7) << 4))) = pk;
        }
        psum += __shfl_xor(psum, 16);
        psum += __shfl_xor(psum, 32);
        if (resc) {
            float fs = __builtin_amdgcn_exp2f(mrow - newm);
            srow_ = srow_ * fs + psum;
            mrow = newm;
#pragma unroll
            for (int r = 0; r < 4; r++) {
                float fb = __shfl(fs, (l >> 4) * 4 + r);
#pragma unroll
                for (int nf = 0; nf < 4; ++nf) o[nf][r] *= fb;
            }
        } else {
            srow_ += psum;
        }

#pragma unroll
        for (int kc = 0; kc < 2; ++kc) {
            int co = (kc * 32 + (l >> 4) * 8) * 2;
            int prow = l & 15;
            u16x8 pa = *(const u16x8*)((const char*)Ps[w] + ((prow * 128 + co) ^ ((prow & 7) << 4)));
#pragma unroll
            for (int nf = 0; nf < 4; ++nf) {
                int row = nf * 16 + (l & 15);
                u16x8 vb = *(const u16x8*)((const char*)Vs + row * 128 + (co ^ ((row & 7) << 4)));
                o[nf] = mfma_bf16(pa, vb, o[nf]);
            }
        }
        __syncthreads();
    }

    float inv = 1.0f / srow_;
#pragma unroll
    for (int r = 0; r < 4; r++) {
        float sb = __shfl(inv, (l >> 4) * 4 + r);
        int row = qstart + qrow0 + (l >> 4) * 4 + r;
#pragma unroll
        for (int nf = 0; nf < 4; ++nf) {
            int col = hq * 64 + nf * 16 + (l & 15);
            y[(rowbase + row) * 1024 + col] = f2bf(o[nf][r] * sb);
        }
    }
}

// ---------------- host launch ----------------

extern "C" void kernel_launch(void* const* d_in, const int* in_sizes, int n_in,
                              void* d_out, int out_size, void* d_ws, size_t ws_size,
                              hipStream_t stream) {
    const float* x  = (const float*)d_in[0];
    const float* wq = (const float*)d_in[1];
    const float* bq = (const float*)d_in[2];
    const float* wk = (const float*)d_in[3];
    const float* bk = (const float*)d_in[4];
    const float* wv = (const float*)d_in[5];
    const float* bv = (const float*)d_in[6];
    const float* wo = (const float*)d_in[7];
    const float* bo = (const float*)d_in[8];
    float* out = (float*)d_out;

    char* p = (char*)d_ws;
    u16* xb     = (u16*)p;   p += (size_t)8192 * 1024 * 2;   // x bf16
    u16* wqkvt  = (u16*)p;   p += (size_t)1536 * 1024 * 2;   // [n][k] bf16 (q,k,v concat)
    u16* wot    = (u16*)p;   p += (size_t)1024 * 1024 * 2;   // wo^T bf16
    float* bqkv = (float*)p; p += 8192;                      // 1536 fp32 (padded)
    u16* qkvb   = (u16*)p;   p += (size_t)8192 * 1536 * 2;   // QKV bf16 (V-section unused)
    u16* vtb    = (u16*)p;   p += (size_t)512 * 4096 * 2;    // V^T bf16
    u16* yb     = (u16*)p;                                   // attn out bf16

    prep_kernel<<<8838, 256, 0, stream>>>(x, wq, bq, wk, bk, wv, bv, wo,
                                          xb, wqkvt, wot, bqkv);

    // Q columns pre-scaled by 0.125*log2(e); V n-tiles written transposed to vtb
    gemm_bt<false, true><<<dim3(12, 64), 256, 0, stream>>>(xb, wqkvt, qkvb, bqkv, vtb,
                                                           8192, 1536, 1024, 1024, 0.18033688f);
    attn_kernel<<<dim3(64, 8, 2), 512, 0, stream>>>(qkvb, vtb, yb);
    gemm_bt<true, false><<<dim3(8, 64), 256, 0, stream>>>(yb, wot, out, bo, nullptr,
                                                          8192, 1024, 1024, 0, 1.0f);
}

// Round 17
// 107.182 us; speedup vs baseline: 1.0854x; 1.0075x over previous
//
#include <hip/hip_runtime.h>

typedef unsigned short u16;
typedef u16 u16x4 __attribute__((ext_vector_type(4)));
typedef u16 u16x8 __attribute__((ext_vector_type(8)));
typedef __bf16 bf16x8 __attribute__((ext_vector_type(8)));
typedef float f32x4 __attribute__((ext_vector_type(4)));

#define DEVINL static __device__ __forceinline__

DEVINL u16 f2bf(float f) {
    unsigned u = __builtin_bit_cast(unsigned, f);
    u += 0x7fff + ((u >> 16) & 1);           // RNE
    return (u16)(u >> 16);
}

DEVINL u16 pbf(float f) {                    // round-half-up, for P in [0, 2^8]
    unsigned u = __builtin_bit_cast(unsigned, f);
    return (u16)((u + 0x8000) >> 16);
}

DEVINL f32x4 mfma_bf16(u16x8 a, u16x8 b, f32x4 c) {
    return __builtin_amdgcn_mfma_f32_16x16x32_bf16(
        __builtin_bit_cast(bf16x8, a), __builtin_bit_cast(bf16x8, b), c, 0, 0, 0);
}

DEVINL void gload16(const void* g, void* lds) {
    __builtin_amdgcn_global_load_lds(
        (const __attribute__((address_space(1))) void*)g,
        (__attribute__((address_space(3))) void*)lds, 16, 0, 0);
}

// ---------------- unified preprocessing kernel (R13: fused, -9.6us) ----------------

DEVINL void twt_body(const float* __restrict__ src, u16* __restrict__ dst,
                     int N, int rowOff, int bx, int by, int tid, float (*t)[65]) {
    int k0 = bx * 64, n0 = by * 64;
#pragma unroll
    for (int j = 0; j < 16; j++) {
        int idx = j * 256 + tid; int r = idx >> 6, c = idx & 63;
        t[r][c] = src[(size_t)(k0 + r) * N + n0 + c];
    }
    __syncthreads();
#pragma unroll
    for (int j = 0; j < 16; j++) {
        int idx = j * 256 + tid; int r = idx >> 6, c = idx & 63;
        dst[(size_t)(rowOff + n0 + r) * 1024 + k0 + c] = f2bf(t[c][r]);
    }
}

__global__ void prep_kernel(const float* __restrict__ x,
                            const float* __restrict__ wq, const float* __restrict__ bq,
                            const float* __restrict__ wk, const float* __restrict__ bk,
                            const float* __restrict__ wv, const float* __restrict__ bv,
                            const float* __restrict__ wo,
                            u16* __restrict__ xb, u16* __restrict__ wqkvt,
                            u16* __restrict__ wot, float* __restrict__ bqkv) {
    __shared__ float t[64][65];
    int bid = blockIdx.x, tid = threadIdx.x;
    if (bid < 8192) {
        int idx = bid * 256 + tid;
        float4 a = ((const float4*)x)[idx];
        u16x4 o;
        o[0] = f2bf(a.x); o[1] = f2bf(a.y); o[2] = f2bf(a.z); o[3] = f2bf(a.w);
        ((u16x4*)xb)[idx] = o;
    } else if (bid < 8448) {
        int id = bid - 8192; twt_body(wq, wqkvt, 1024, 0, id & 15, id >> 4, tid, t);
    } else if (bid < 8512) {
        int id = bid - 8448; twt_body(wk, wqkvt, 256, 1024, id & 15, id >> 4, tid, t);
    } else if (bid < 8576) {
        int id = bid - 8512; twt_body(wv, wqkvt, 256, 1280, id & 15, id >> 4, tid, t);
    } else if (bid < 8832) {
        int id = bid - 8576; twt_body(wo, wot, 1024, 0, id & 15, id >> 4, tid, t);
    } else {
        int i = (bid - 8832) * 256 + tid;
        if (i < 1024) bqkv[i] = bq[i];
        else if (i < 1280) bqkv[i] = bk[i - 1024];
        else if (i < 1536) bqkv[i] = bv[i - 1280];
    }
}

// ---------------- MFMA GEMM (R10 structure + R14 VSPLIT V-transpose epilogue) ----------------

template <bool F32OUT, bool VSPLIT>
__global__ __launch_bounds__(256, 2) void gemm_bt(
    const u16* __restrict__ A, const u16* __restrict__ Bt, void* __restrict__ Cp,
    const float* __restrict__ bias, u16* __restrict__ vt,
    int M, int N, int K, int qn, float qscale) {
    __shared__ __align__(16) u16 As[128 * 64];
    __shared__ __align__(16) u16 Bs[128 * 64];
    int tid = threadIdx.x; int l = tid & 63; int w = tid >> 6;

    int nwg = gridDim.x * gridDim.y;
    int lin = blockIdx.y * gridDim.x + blockIdx.x;
    int q_ = nwg >> 3, r_ = nwg & 7;
    int xcd = lin & 7, i_ = lin >> 3;
    int wgid = (xcd < r_ ? xcd * (q_ + 1) : r_ * (q_ + 1) + (xcd - r_) * q_) + i_;
    int m0 = (wgid / gridDim.x) * 128, n0 = (wgid % gridDim.x) * 128;

    int wm = (w >> 1) * 64, wn = (w & 1) * 64;
    f32x4 acc[4][4] = {};

    int srow[4], scol[4];
#pragma unroll
    for (int c = 0; c < 4; c++) {
        int b = (w * 4 + c) * 1024 + l * 16;
        int row = b >> 7, inner = b & 127;
        srow[c] = row;
        scol[c] = (inner ^ ((row & 7) << 4)) >> 1;
    }
    int nk = K >> 6;
    for (int kt = 0; kt < nk; ++kt) {
        int kb = kt << 6;
#pragma unroll
        for (int c = 0; c < 4; c++) {
            gload16(A + (size_t)(m0 + srow[c]) * K + kb + scol[c], (char*)As + (w * 4 + c) * 1024);
            gload16(Bt + (size_t)(n0 + srow[c]) * K + kb + scol[c], (char*)Bs + (w * 4 + c) * 1024);
        }
        __syncthreads();
#pragma unroll
        for (int kc = 0; kc < 2; ++kc) {
            int co = (kc * 32 + (l >> 4) * 8) * 2;
            u16x8 af[4], bf[4];
#pragma unroll
            for (int mf = 0; mf < 4; ++mf) {
                int row = wm + mf * 16 + (l & 15);
                af[mf] = *(const u16x8*)((const char*)As + row * 128 + (co ^ ((row & 7) << 4)));
            }
#pragma unroll
            for (int nf = 0; nf < 4; ++nf) {
                int row = wn + nf * 16 + (l & 15);
                bf[nf] = *(const u16x8*)((const char*)Bs + row * 128 + (co ^ ((row & 7) << 4)));
            }
#pragma unroll
            for (int mf = 0; mf < 4; ++mf)
#pragma unroll
                for (int nf = 0; nf < 4; ++nf)
                    acc[mf][nf] = mfma_bf16(af[mf], bf[nf], acc[mf][nf]);
        }
        __syncthreads();
    }
#pragma unroll
    for (int mf = 0; mf < 4; ++mf) {
#pragma unroll
        for (int nf = 0; nf < 4; ++nf) {
            int col = n0 + wn + nf * 16 + (l & 15);
            float bv = bias ? bias[col] : 0.0f;
            float scl = (col < qn) ? qscale : 1.0f;   // uniform per 16-lane group
            if (VSPLIT && col >= 1280) {
                int row0 = m0 + wm + mf * 16 + (l >> 4) * 4;
                int b_ = row0 >> 12, t_ = row0 & 4095;
                u16x4 pk;
#pragma unroll
                for (int r = 0; r < 4; r++) pk[r] = f2bf(acc[mf][nf][r] + bv);
                *(u16x4*)(vt + ((size_t)(b_ * 256 + (col - 1280)) << 12) + t_) = pk;
            } else {
#pragma unroll
                for (int r = 0; r < 4; r++) {
                    int row = m0 + wm + mf * 16 + (l >> 4) * 4 + r;
                    float v = (acc[mf][nf][r] + bv) * scl;
                    if (F32OUT) ((float*)Cp)[(size_t)row * N + col] = v;
                    else        ((u16*)Cp)[(size_t)row * N + col] = f2bf(v);
                }
            }
        }
    }
}

// ---------------- banded GQA flash attention: R8 shape at tile-PAIR granularity ----------------
// block = (qblock 64, head-pair, b); grid 64x8x2 = 1024. 8 waves = 2 q-heads x 4
// q-frags. Same proven {stage -> sync -> compute -> sync} loop, but per round a
// PAIR of 64-row K/V tiles is staged (one sync covers both tile-computes; P is
// wave-local so no barrier between them): barrier crossings 18 -> 10 per block.
// LDS 48KB -> 3 blocks/CU (vs 4; mild residency trade, unlike R15's 4->1).
// T5 setprio(1/0) around MFMA clusters (3 co-resident blocks arbitrate; m191 +4-7%).
// Compile-time 5 anchored pair-rounds, block-uniform validity guards.

__global__ __launch_bounds__(512, 4) void attn_kernel(
    const u16* __restrict__ qkv, const u16* __restrict__ vt, u16* __restrict__ y) {
    __shared__ __align__(16) u16 Ks[2][64 * 64];
    __shared__ __align__(16) u16 Vs[2][64 * 64];
    __shared__ __align__(16) u16 Ps[8][16 * 64];
    int tid = threadIdx.x, l = tid & 63, w = tid >> 6;
    int qb = ((blockIdx.x & 7) << 3) | (blockIdx.x >> 3);
    int h = blockIdx.y >> 1, hp = blockIdx.y & 1, b = blockIdx.z;
    int qstart = qb * 64;
    size_t rowbase = (size_t)b * 4096;
    int hq = h * 4 + hp * 2 + (w >> 2);
    int qrow0 = (w & 3) * 16;

    u16x8 qf_[2];
#pragma unroll
    for (int kc = 0; kc < 2; ++kc)
        qf_[kc] = *(const u16x8*)(qkv + (rowbase + qstart + qrow0 + (l & 15)) * 1536
                                  + hq * 64 + kc * 32 + (l >> 4) * 8);

    f32x4 o[4] = {};
    float mrow = -__builtin_inff(), srow_ = 0.f;

    const u16* kbase_ptr = qkv + 1024 + h * 64;
    const u16* vbase_ptr = vt + (size_t)((b * 4 + h) * 64) * 4096;

    int sb_ = w * 1024 + l * 16;
    int g_row = sb_ >> 7, g_inner = sb_ & 127;
    int g_col = (g_inner ^ ((g_row & 7) << 4)) >> 1;

#define COMPUTE_TILE(kstart_, Kb_, Vb_)                                                   \
    do {                                                                                  \
        f32x4 st[4] = {};                                                                 \
        __builtin_amdgcn_s_setprio(1);                                                    \
        _Pragma("unroll")                                                                 \
        for (int kc = 0; kc < 2; ++kc) {                                                  \
            int co = (kc * 32 + (l >> 4) * 8) * 2;                                        \
            _Pragma("unroll")                                                             \
            for (int kf = 0; kf < 4; ++kf) {                                              \
                int row = kf * 16 + (l & 15);                                             \
                u16x8 kfr = *(const u16x8*)((const char*)(Kb_) + row * 128                \
                                            + (co ^ ((row & 7) << 4)));                   \
                st[kf] = mfma_bf16(kfr, qf_[kc], st[kf]);                                 \
            }                                                                             \
        }                                                                                 \
        __builtin_amdgcn_s_setprio(0);                                                    \
        bool mlo = ((kstart_) == qstart - 256);                                           \
        bool mhi = ((kstart_) == qstart + 256);                                           \
        int qoff = qrow0 + (l & 15);                                                      \
        float pmax = -1e30f;                                                              \
        float sv[4][4];                                                                   \
        _Pragma("unroll")                                                                 \
        for (int kf = 0; kf < 4; ++kf)                                                    \
            _Pragma("unroll")                                                             \
            for (int r = 0; r < 4; r++) {                                                 \
                int koff = kf * 16 + (l >> 4) * 4 + r;                                    \
                float v = st[kf][r];                                                      \
                if (mlo && koff < qoff) v = -1e30f;                                       \
                if (mhi && koff > qoff) v = -1e30f;                                       \
                sv[kf][r] = v;                                                            \
                pmax = fmaxf(pmax, v);                                                    \
            }                                                                             \
        pmax = fmaxf(pmax, __shfl_xor(pmax, 16));                                         \
        pmax = fmaxf(pmax, __shfl_xor(pmax, 32));                                         \
        bool resc = !__all(pmax - mrow <= 8.0f);                                          \
        float newm = resc ? fmaxf(mrow, pmax) : mrow;                                     \
        float psum = 0.f;                                                                 \
        _Pragma("unroll")                                                                 \
        for (int kf = 0; kf < 4; ++kf) {                                                  \
            u16x4 pk;                                                                     \
            _Pragma("unroll")                                                             \
            for (int r = 0; r < 4; r++) {                                                 \
                float e = __builtin_amdgcn_exp2f(sv[kf][r] - newm);                       \
                psum += e;                                                                \
                pk[r] = pbf(e);                                                           \
            }                                                                             \
            int prow_ = l & 15;                                                           \
            int keyc = kf * 16 + (l >> 4) * 4;                                            \
            *(u16x4*)((char*)Ps[w] + ((prow_ * 128 + keyc * 2) ^ ((prow_ & 7) << 4))) = pk; \
        }                                                                                 \
        psum += __shfl_xor(psum, 16);                                                     \
        psum += __shfl_xor(psum, 32);                                                     \
        if (resc) {                                                                       \
            float fs = __builtin_amdgcn_exp2f(mrow - newm);                               \
            srow_ = srow_ * fs + psum;                                                    \
            mrow = newm;                                                                  \
            _Pragma("unroll")                                                             \
            for (int r = 0; r < 4; r++) {                                                 \
                float fb = __shfl(fs, (l >> 4) * 4 + r);                                  \
                _Pragma("unroll")                                                         \
                for (int nf = 0; nf < 4; ++nf) o[nf][r] *= fb;                            \
            }                                                                             \
        } else {                                                                          \
            srow_ += psum;                                                                \
        }                                                                                 \
        __builtin_amdgcn_s_setprio(1);                                                    \
        _Pragma("unroll")                                                                 \
        for (int kc = 0; kc < 2; ++kc) {                                                  \
            int co = (kc * 32 + (l >> 4) * 8) * 2;                                        \
            int prow_ = l & 15;                                                           \
            u16x8 pa = *(const u16x8*)((const char*)Ps[w]                                 \
                         + ((prow_ * 128 + co) ^ ((prow_ & 7) << 4)));                    \
            _Pragma("unroll")                                                             \
            for (int nf = 0; nf < 4; ++nf) {                                              \
                int row = nf * 16 + (l & 15);                                             \
                u16x8 vb = *(const u16x8*)((const char*)(Vb_) + row * 128                 \
                                           + (co ^ ((row & 7) << 4)));                    \
                o[nf] = mfma_bf16(pa, vb, o[nf]);                                         \
            }                                                                             \
        }                                                                                 \
        __builtin_amdgcn_s_setprio(0);                                                    \
    } while (0)

#pragma unroll
    for (int j = 0; j < 5; ++j) {
        int k0 = qstart - 256 + j * 128;
        int k1 = k0 + 64;
        bool v0 = (k0 >= 0 && k0 <= 4032);                  // block-uniform
        bool v1 = (j < 4) && (k1 >= 0 && k1 <= 4032);       // j=4's k1 is outside window
        if (!v0 && !v1) continue;
        if (v0) {
            gload16(kbase_ptr + (rowbase + k0 + g_row) * 1536 + g_col, (char*)Ks[0] + w * 1024);
            gload16(vbase_ptr + (size_t)g_row * 4096 + k0 + g_col, (char*)Vs[0] + w * 1024);
        }
        if (v1) {
            gload16(kbase_ptr + (rowbase + k1 + g_row) * 1536 + g_col, (char*)Ks[1] + w * 1024);
            gload16(vbase_ptr + (size_t)g_row * 4096 + k1 + g_col, (char*)Vs[1] + w * 1024);
        }
        __syncthreads();
        if (v0) COMPUTE_TILE(k0, Ks[0], Vs[0]);
        if (v1) COMPUTE_TILE(k1, Ks[1], Vs[1]);
        __syncthreads();
    }
#undef COMPUTE_TILE

    float inv = 1.0f / srow_;
#pragma unroll
    for (int r = 0; r < 4; r++) {
        float sb = __shfl(inv, (l >> 4) * 4 + r);
        int row = qstart + qrow0 + (l >> 4) * 4 + r;
#pragma unroll
        for (int nf = 0; nf < 4; ++nf) {
            int col = hq * 64 + nf * 16 + (l & 15);
            y[(rowbase + row) * 1024 + col] = f2bf(o[nf][r] * sb);
        }
    }
}

// ---------------- host launch ----------------

extern "C" void kernel_launch(void* const* d_in, const int* in_sizes, int n_in,
                              void* d_out, int out_size, void* d_ws, size_t ws_size,
                              hipStream_t stream) {
    const float* x  = (const float*)d_in[0];
    const float* wq = (const float*)d_in[1];
    const float* bq = (const float*)d_in[2];
    const float* wk = (const float*)d_in[3];
    const float* bk = (const float*)d_in[4];
    const float* wv = (const float*)d_in[5];
    const float* bv = (const float*)d_in[6];
    const float* wo = (const float*)d_in[7];
    const float* bo = (const float*)d_in[8];
    float* out = (float*)d_out;

    char* p = (char*)d_ws;
    u16* xb     = (u16*)p;   p += (size_t)8192 * 1024 * 2;   // x bf16
    u16* wqkvt  = (u16*)p;   p += (size_t)1536 * 1024 * 2;   // [n][k] bf16 (q,k,v concat)
    u16* wot    = (u16*)p;   p += (size_t)1024 * 1024 * 2;   // wo^T bf16
    float* bqkv = (float*)p; p += 8192;                      // 1536 fp32 (padded)
    u16* qkvb   = (u16*)p;   p += (size_t)8192 * 1536 * 2;   // QKV bf16 (V-section unused)
    u16* vtb    = (u16*)p;   p += (size_t)512 * 4096 * 2;    // V^T bf16
    u16* yb     = (u16*)p;                                   // attn out bf16

    prep_kernel<<<8838, 256, 0, stream>>>(x, wq, bq, wk, bk, wv, bv, wo,
                                          xb, wqkvt, wot, bqkv);

    // Q columns pre-scaled by 0.125*log2(e); V n-tiles written transposed to vtb
    gemm_bt<false, true><<<dim3(12, 64), 256, 0, stream>>>(xb, wqkvt, qkvb, bqkv, vtb,
                                                           8192, 1536, 1024, 1024, 0.18033688f);
    attn_kernel<<<dim3(64, 8, 2), 512, 0, stream>>>(qkvb, vtb, yb);
    gemm_bt<true, false><<<dim3(8, 64), 256, 0, stream>>>(yb, wot, out, bo, nullptr,
                                                          8192, 1024, 1024, 0, 1.0f);
}

// Round 18
// 105.896 us; speedup vs baseline: 1.0986x; 1.0121x over previous
//
#include <hip/hip_runtime.h>

typedef unsigned short u16;
typedef u16 u16x4 __attribute__((ext_vector_type(4)));
typedef u16 u16x8 __attribute__((ext_vector_type(8)));
typedef __bf16 bf16x8 __attribute__((ext_vector_type(8)));
typedef float f32x4 __attribute__((ext_vector_type(4)));

#define DEVINL static __device__ __forceinline__

DEVINL u16 f2bf(float f) {
    unsigned u = __builtin_bit_cast(unsigned, f);
    u += 0x7fff + ((u >> 16) & 1);           // RNE
    return (u16)(u >> 16);
}

DEVINL u16 pbf(float f) {                    // round-half-up, for P in [0, 2^8]
    unsigned u = __builtin_bit_cast(unsigned, f);
    return (u16)((u + 0x8000) >> 16);
}

DEVINL f32x4 mfma_bf16(u16x8 a, u16x8 b, f32x4 c) {
    return __builtin_amdgcn_mfma_f32_16x16x32_bf16(
        __builtin_bit_cast(bf16x8, a), __builtin_bit_cast(bf16x8, b), c, 0, 0, 0);
}

DEVINL void gload16(const void* g, void* lds) {
    __builtin_amdgcn_global_load_lds(
        (const __attribute__((address_space(1))) void*)g,
        (__attribute__((address_space(3))) void*)lds, 16, 0, 0);
}

// ---------------- unified preprocessing kernel (R13 fused; R18: 2x float4/thread x-convert) ----
// Sections by blockIdx.x:
//  [0, 4096)        : x fp32 -> bf16 (2x float4/thread, 32B/lane)
//  [4096, 4352)     : transpose+cvt wq -> wqkvt rows [0,1024)
//  [4352, 4416)     : transpose+cvt wk -> wqkvt rows [1024,1280)
//  [4416, 4480)     : transpose+cvt wv -> wqkvt rows [1280,1536)
//  [4480, 4736)     : transpose+cvt wo -> wot
//  [4736, 4742)     : pack biases

DEVINL void twt_body(const float* __restrict__ src, u16* __restrict__ dst,
                     int N, int rowOff, int bx, int by, int tid, float (*t)[65]) {
    int k0 = bx * 64, n0 = by * 64;
#pragma unroll
    for (int j = 0; j < 16; j++) {
        int idx = j * 256 + tid; int r = idx >> 6, c = idx & 63;
        t[r][c] = src[(size_t)(k0 + r) * N + n0 + c];
    }
    __syncthreads();
#pragma unroll
    for (int j = 0; j < 16; j++) {
        int idx = j * 256 + tid; int r = idx >> 6, c = idx & 63;
        dst[(size_t)(rowOff + n0 + r) * 1024 + k0 + c] = f2bf(t[c][r]);
    }
}

__global__ void prep_kernel(const float* __restrict__ x,
                            const float* __restrict__ wq, const float* __restrict__ bq,
                            const float* __restrict__ wk, const float* __restrict__ bk,
                            const float* __restrict__ wv, const float* __restrict__ bv,
                            const float* __restrict__ wo,
                            u16* __restrict__ xb, u16* __restrict__ wqkvt,
                            u16* __restrict__ wot, float* __restrict__ bqkv) {
    __shared__ float t[64][65];
    int bid = blockIdx.x, tid = threadIdx.x;
    if (bid < 4096) {
        int idx = (bid * 256 + tid) * 2;
#pragma unroll
        for (int u = 0; u < 2; ++u) {
            float4 a = ((const float4*)x)[idx + u];
            u16x4 o;
            o[0] = f2bf(a.x); o[1] = f2bf(a.y); o[2] = f2bf(a.z); o[3] = f2bf(a.w);
            ((u16x4*)xb)[idx + u] = o;
        }
    } else if (bid < 4352) {
        int id = bid - 4096; twt_body(wq, wqkvt, 1024, 0, id & 15, id >> 4, tid, t);
    } else if (bid < 4416) {
        int id = bid - 4352; twt_body(wk, wqkvt, 256, 1024, id & 15, id >> 4, tid, t);
    } else if (bid < 4480) {
        int id = bid - 4416; twt_body(wv, wqkvt, 256, 1280, id & 15, id >> 4, tid, t);
    } else if (bid < 4736) {
        int id = bid - 4480; twt_body(wo, wot, 1024, 0, id & 15, id >> 4, tid, t);
    } else {
        int i = (bid - 4736) * 256 + tid;
        if (i < 1024) bqkv[i] = bq[i];
        else if (i < 1280) bqkv[i] = bk[i - 1024];
        else if (i < 1536) bqkv[i] = bv[i - 1280];
    }
}

// ---------------- MFMA GEMM (R10 structure + R14 VSPLIT V-transpose epilogue) ----------------
// Bijective chunked XCD swizzle (m204): ~10us win measured R5->R6.
// VSPLIT: cols >= 1280 (whole n-tiles) written directly transposed into vt,
// replacing the separate tv_kernel pass (R14: -2us); qkvb V-section never read.

template <bool F32OUT, bool VSPLIT>
__global__ __launch_bounds__(256, 2) void gemm_bt(
    const u16* __restrict__ A, const u16* __restrict__ Bt, void* __restrict__ Cp,
    const float* __restrict__ bias, u16* __restrict__ vt,
    int M, int N, int K, int qn, float qscale) {
    __shared__ __align__(16) u16 As[128 * 64];
    __shared__ __align__(16) u16 Bs[128 * 64];
    int tid = threadIdx.x; int l = tid & 63; int w = tid >> 6;

    int nwg = gridDim.x * gridDim.y;
    int lin = blockIdx.y * gridDim.x + blockIdx.x;
    int q_ = nwg >> 3, r_ = nwg & 7;
    int xcd = lin & 7, i_ = lin >> 3;
    int wgid = (xcd < r_ ? xcd * (q_ + 1) : r_ * (q_ + 1) + (xcd - r_) * q_) + i_;
    int m0 = (wgid / gridDim.x) * 128, n0 = (wgid % gridDim.x) * 128;

    int wm = (w >> 1) * 64, wn = (w & 1) * 64;
    f32x4 acc[4][4] = {};

    int srow[4], scol[4];
#pragma unroll
    for (int c = 0; c < 4; c++) {
        int b = (w * 4 + c) * 1024 + l * 16;
        int row = b >> 7, inner = b & 127;
        srow[c] = row;
        scol[c] = (inner ^ ((row & 7) << 4)) >> 1;
    }
    int nk = K >> 6;
    for (int kt = 0; kt < nk; ++kt) {
        int kb = kt << 6;
#pragma unroll
        for (int c = 0; c < 4; c++) {
            gload16(A + (size_t)(m0 + srow[c]) * K + kb + scol[c], (char*)As + (w * 4 + c) * 1024);
            gload16(Bt + (size_t)(n0 + srow[c]) * K + kb + scol[c], (char*)Bs + (w * 4 + c) * 1024);
        }
        __syncthreads();
#pragma unroll
        for (int kc = 0; kc < 2; ++kc) {
            int co = (kc * 32 + (l >> 4) * 8) * 2;
            u16x8 af[4], bf[4];
#pragma unroll
            for (int mf = 0; mf < 4; ++mf) {
                int row = wm + mf * 16 + (l & 15);
                af[mf] = *(const u16x8*)((const char*)As + row * 128 + (co ^ ((row & 7) << 4)));
            }
#pragma unroll
            for (int nf = 0; nf < 4; ++nf) {
                int row = wn + nf * 16 + (l & 15);
                bf[nf] = *(const u16x8*)((const char*)Bs + row * 128 + (co ^ ((row & 7) << 4)));
            }
#pragma unroll
            for (int mf = 0; mf < 4; ++mf)
#pragma unroll
                for (int nf = 0; nf < 4; ++nf)
                    acc[mf][nf] = mfma_bf16(af[mf], bf[nf], acc[mf][nf]);
        }
        __syncthreads();
    }
#pragma unroll
    for (int mf = 0; mf < 4; ++mf) {
#pragma unroll
        for (int nf = 0; nf < 4; ++nf) {
            int col = n0 + wn + nf * 16 + (l & 15);
            float bv = bias ? bias[col] : 0.0f;
            float scl = (col < qn) ? qscale : 1.0f;   // uniform per 16-lane group
            if (VSPLIT && col >= 1280) {
                int row0 = m0 + wm + mf * 16 + (l >> 4) * 4;
                int b_ = row0 >> 12, t_ = row0 & 4095;
                u16x4 pk;
#pragma unroll
                for (int r = 0; r < 4; r++) pk[r] = f2bf(acc[mf][nf][r] + bv);
                *(u16x4*)(vt + ((size_t)(b_ * 256 + (col - 1280)) << 12) + t_) = pk;
            } else {
#pragma unroll
                for (int r = 0; r < 4; r++) {
                    int row = m0 + wm + mf * 16 + (l >> 4) * 4 + r;
                    float v = (acc[mf][nf][r] + bv) * scl;
                    if (F32OUT) ((float*)Cp)[(size_t)row * N + col] = v;
                    else        ((u16*)Cp)[(size_t)row * N + col] = f2bf(v);
                }
            }
        }
    }
}

// ---------------- banded GQA flash attention (R17: tile-pair rounds, best = 41.1us) ----------
// block = (qblock 64, head-pair, b); grid 64x8x2 = 1024. 8 waves = 2 q-heads x 4
// q-frags. Per round a PAIR of 64-row K/V tiles staged, one sync covers both
// tile-computes (P wave-local): barriers 18 -> 10. LDS 48KB -> 3 blocks/CU.
// T5 setprio around MFMA clusters. 10 structural variants probed; this is the floor.

__global__ __launch_bounds__(512, 4) void attn_kernel(
    const u16* __restrict__ qkv, const u16* __restrict__ vt, u16* __restrict__ y) {
    __shared__ __align__(16) u16 Ks[2][64 * 64];
    __shared__ __align__(16) u16 Vs[2][64 * 64];
    __shared__ __align__(16) u16 Ps[8][16 * 64];
    int tid = threadIdx.x, l = tid & 63, w = tid >> 6;
    int qb = ((blockIdx.x & 7) << 3) | (blockIdx.x >> 3);
    int h = blockIdx.y >> 1, hp = blockIdx.y & 1, b = blockIdx.z;
    int qstart = qb * 64;
    size_t rowbase = (size_t)b * 4096;
    int hq = h * 4 + hp * 2 + (w >> 2);
    int qrow0 = (w & 3) * 16;

    u16x8 qf_[2];
#pragma unroll
    for (int kc = 0; kc < 2; ++kc)
        qf_[kc] = *(const u16x8*)(qkv + (rowbase + qstart + qrow0 + (l & 15)) * 1536
                                  + hq * 64 + kc * 32 + (l >> 4) * 8);

    f32x4 o[4] = {};
    float mrow = -__builtin_inff(), srow_ = 0.f;

    const u16* kbase_ptr = qkv + 1024 + h * 64;
    const u16* vbase_ptr = vt + (size_t)((b * 4 + h) * 64) * 4096;

    int sb_ = w * 1024 + l * 16;
    int g_row = sb_ >> 7, g_inner = sb_ & 127;
    int g_col = (g_inner ^ ((g_row & 7) << 4)) >> 1;

#define COMPUTE_TILE(kstart_, Kb_, Vb_)                                                   \
    do {                                                                                  \
        f32x4 st[4] = {};                                                                 \
        __builtin_amdgcn_s_setprio(1);                                                    \
        _Pragma("unroll")                                                                 \
        for (int kc = 0; kc < 2; ++kc) {                                                  \
            int co = (kc * 32 + (l >> 4) * 8) * 2;                                        \
            _Pragma("unroll")                                                             \
            for (int kf = 0; kf < 4; ++kf) {                                              \
                int row = kf * 16 + (l & 15);                                             \
                u16x8 kfr = *(const u16x8*)((const char*)(Kb_) + row * 128                \
                                            + (co ^ ((row & 7) << 4)));                   \
                st[kf] = mfma_bf16(kfr, qf_[kc], st[kf]);                                 \
            }                                                                             \
        }                                                                                 \
        __builtin_amdgcn_s_setprio(0);                                                    \
        bool mlo = ((kstart_) == qstart - 256);                                           \
        bool mhi = ((kstart_) == qstart + 256);                                           \
        int qoff = qrow0 + (l & 15);                                                      \
        float pmax = -1e30f;                                                              \
        float sv[4][4];                                                                   \
        _Pragma("unroll")                                                                 \
        for (int kf = 0; kf < 4; ++kf)                                                    \
            _Pragma("unroll")                                                             \
            for (int r = 0; r < 4; r++) {                                                 \
                int koff = kf * 16 + (l >> 4) * 4 + r;                                    \
                float v = st[kf][r];                                                      \
                if (mlo && koff < qoff) v = -1e30f;                                       \
                if (mhi && koff > qoff) v = -1e30f;                                       \
                sv[kf][r] = v;                                                            \
                pmax = fmaxf(pmax, v);                                                    \
            }                                                                             \
        pmax = fmaxf(pmax, __shfl_xor(pmax, 16));                                         \
        pmax = fmaxf(pmax, __shfl_xor(pmax, 32));                                         \
        bool resc = !__all(pmax - mrow <= 8.0f);                                          \
        float newm = resc ? fmaxf(mrow, pmax) : mrow;                                     \
        float psum = 0.f;                                                                 \
        _Pragma("unroll")                                                                 \
        for (int kf = 0; kf < 4; ++kf) {                                                  \
            u16x4 pk;                                                                     \
            _Pragma("unroll")                                                             \
            for (int r = 0; r < 4; r++) {                                                 \
                float e = __builtin_amdgcn_exp2f(sv[kf][r] - newm);                       \
                psum += e;                                                                \
                pk[r] = pbf(e);                                                           \
            }                                                                             \
            int prow_ = l & 15;                                                           \
            int keyc = kf * 16 + (l >> 4) * 4;                                            \
            *(u16x4*)((char*)Ps[w] + ((prow_ * 128 + keyc * 2) ^ ((prow_ & 7) << 4))) = pk; \
        }                                                                                 \
        psum += __shfl_xor(psum, 16);                                                     \
        psum += __shfl_xor(psum, 32);                                                     \
        if (resc) {                                                                       \
            float fs = __builtin_amdgcn_exp2f(mrow - newm);                               \
            srow_ = srow_ * fs + psum;                                                    \
            mrow = newm;                                                                  \
            _Pragma("unroll")                                                             \
            for (int r = 0; r < 4; r++) {                                                 \
                float fb = __shfl(fs, (l >> 4) * 4 + r);                                  \
                _Pragma("unroll")                                                         \
                for (int nf = 0; nf < 4; ++nf) o[nf][r] *= fb;                            \
            }                                                                             \
        } else {                                                                          \
            srow_ += psum;                                                                \
        }                                                                                 \
        __builtin_amdgcn_s_setprio(1);                                                    \
        _Pragma("unroll")                                                                 \
        for (int kc = 0; kc < 2; ++kc) {                                                  \
            int co = (kc * 32 + (l >> 4) * 8) * 2;                                        \
            int prow_ = l & 15;                                                           \
            u16x8 pa = *(const u16x8*)((const char*)Ps[w]                                 \
                         + ((prow_ * 128 + co) ^ ((prow_ & 7) << 4)));                    \
            _Pragma("unroll")                                                             \
            for (int nf = 0; nf < 4; ++nf) {                                              \
                int row = nf * 16 + (l & 15);                                             \
                u16x8 vb = *(const u16x8*)((const char*)(Vb_) + row * 128                 \
                                           + (co ^ ((row & 7) << 4)));                    \
                o[nf] = mfma_bf16(pa, vb, o[nf]);                                         \
            }                                                                             \
        }                                                                                 \
        __builtin_amdgcn_s_setprio(0);                                                    \
    } while (0)

#pragma unroll
    for (int j = 0; j < 5; ++j) {
        int k0 = qstart - 256 + j * 128;
        int k1 = k0 + 64;
        bool v0 = (k0 >= 0 && k0 <= 4032);                  // block-uniform
        bool v1 = (j < 4) && (k1 >= 0 && k1 <= 4032);       // j=4's k1 is outside window
        if (!v0 && !v1) continue;
        if (v0) {
            gload16(kbase_ptr + (rowbase + k0 + g_row) * 1536 + g_col, (char*)Ks[0] + w * 1024);
            gload16(vbase_ptr + (size_t)g_row * 4096 + k0 + g_col, (char*)Vs[0] + w * 1024);
        }
        if (v1) {
            gload16(kbase_ptr + (rowbase + k1 + g_row) * 1536 + g_col, (char*)Ks[1] + w * 1024);
            gload16(vbase_ptr + (size_t)g_row * 4096 + k1 + g_col, (char*)Vs[1] + w * 1024);
        }
        __syncthreads();
        if (v0) COMPUTE_TILE(k0, Ks[0], Vs[0]);
        if (v1) COMPUTE_TILE(k1, Ks[1], Vs[1]);
        __syncthreads();
    }
#undef COMPUTE_TILE

    float inv = 1.0f / srow_;
#pragma unroll
    for (int r = 0; r < 4; r++) {
        float sb = __shfl(inv, (l >> 4) * 4 + r);
        int row = qstart + qrow0 + (l >> 4) * 4 + r;
#pragma unroll
        for (int nf = 0; nf < 4; ++nf) {
            int col = hq * 64 + nf * 16 + (l & 15);
            y[(rowbase + row) * 1024 + col] = f2bf(o[nf][r] * sb);
        }
    }
}

// ---------------- host launch ----------------

extern "C" void kernel_launch(void* const* d_in, const int* in_sizes, int n_in,
                              void* d_out, int out_size, void* d_ws, size_t ws_size,
                              hipStream_t stream) {
    const float* x  = (const float*)d_in[0];
    const float* wq = (const float*)d_in[1];
    const float* bq = (const float*)d_in[2];
    const float* wk = (const float*)d_in[3];
    const float* bk = (const float*)d_in[4];
    const float* wv = (const float*)d_in[5];
    const float* bv = (const float*)d_in[6];
    const float* wo = (const float*)d_in[7];
    const float* bo = (const float*)d_in[8];
    float* out = (float*)d_out;

    char* p = (char*)d_ws;
    u16* xb     = (u16*)p;   p += (size_t)8192 * 1024 * 2;   // x bf16
    u16* wqkvt  = (u16*)p;   p += (size_t)1536 * 1024 * 2;   // [n][k] bf16 (q,k,v concat)
    u16* wot    = (u16*)p;   p += (size_t)1024 * 1024 * 2;   // wo^T bf16
    float* bqkv = (float*)p; p += 8192;                      // 1536 fp32 (padded)
    u16* qkvb   = (u16*)p;   p += (size_t)8192 * 1536 * 2;   // QKV bf16 (V-section unused)
    u16* vtb    = (u16*)p;   p += (size_t)512 * 4096 * 2;    // V^T bf16
    u16* yb     = (u16*)p;                                   // attn out bf16

    prep_kernel<<<4742, 256, 0, stream>>>(x, wq, bq, wk, bk, wv, bv, wo,
                                          xb, wqkvt, wot, bqkv);

    // Q columns pre-scaled by 0.125*log2(e); V n-tiles written transposed to vtb
    gemm_bt<false, true><<<dim3(12, 64), 256, 0, stream>>>(xb, wqkvt, qkvb, bqkv, vtb,
                                                           8192, 1536, 1024, 1024, 0.18033688f);
    attn_kernel<<<dim3(64, 8, 2), 512, 0, stream>>>(qkvb, vtb, yb);
    gemm_bt<true, false><<<dim3(8, 64), 256, 0, stream>>>(yb, wot, out, bo, nullptr,
                                                          8192, 1024, 1024, 0, 1.0f);
}